// Round 1
// baseline (1122.494 us; speedup 1.0000x reference)
//
#include <hip/hip_runtime.h>
#include <stdint.h>

#define NTOK 8192
#define DDIM 1024
#define FDIM 2752
#define NEXP 8
#define DF2  5504   // 2F
#define NSLOT 16384 // NTOK * TOPK

typedef __attribute__((ext_vector_type(8))) short bf16x8;
typedef __attribute__((ext_vector_type(4))) float f32x4;
typedef __attribute__((ext_vector_type(4))) unsigned short u16x4;
typedef __attribute__((ext_vector_type(8))) unsigned short u16x8;

// ---- workspace layout (bytes) ----
constexpr size_t XB_OFF   = 0;                                   // x bf16 [NTOK][DDIM]
constexpr size_t XB_SZ    = (size_t)NTOK * DDIM * 2;
constexpr size_t W13T_OFF = XB_OFF + XB_SZ;                      // W13^T bf16 [E][2F][D]
constexpr size_t W13T_SZ  = (size_t)NEXP * DF2 * DDIM * 2;
constexpr size_t W2T_OFF  = W13T_OFF + W13T_SZ;                  // W2^T bf16 [E][D][F]
constexpr size_t W2T_SZ   = (size_t)NEXP * DDIM * FDIM * 2;
constexpr size_t H_OFF    = W2T_OFF + W2T_SZ;                    // h bf16 [NSLOT][F]
constexpr size_t H_SZ     = (size_t)NSLOT * FDIM * 2;
constexpr size_t ST_OFF   = H_OFF + H_SZ;                        // slot_token i32
constexpr size_t SW_OFF   = ST_OFF + (size_t)NSLOT * 4;          // slot_weight f32
constexpr size_t TTI_OFF  = SW_OFF + (size_t)NSLOT * 4;          // per-token top2 idx (int2)
constexpr size_t TTW_OFF  = TTI_OFF + (size_t)NTOK * 8;          // per-token top2 w (float2)
constexpr size_t META_OFF = TTW_OFF + (size_t)NTOK * 8;          // cnt[8], cnt2[8], off[8]
constexpr size_t TS_OFF   = META_OFF + 256;                      // token -> slots (int2)
// y fp32 [NSLOT][DDIM] (64MB) ALIASES the W13T region (90MB): gemm1 is done with
// W13^T before gemm2 runs (same stream), so the reuse is safe within a launch.

__device__ __forceinline__ unsigned short f2bf(float f) {
  unsigned u = __float_as_uint(f);
  u += 0x7FFFu + ((u >> 16) & 1u);     // RNE
  return (unsigned short)(u >> 16);
}

__device__ __forceinline__ void gl_lds16(const void* g, void* l) {
  __builtin_amdgcn_global_load_lds(
      (const __attribute__((address_space(1))) unsigned int*)g,
      (__attribute__((address_space(3))) unsigned int*)l, 16, 0, 0);
}

#define WAIT_VM4 asm volatile("s_waitcnt vmcnt(4)" ::: "memory")
#define WAIT_VM0 asm volatile("s_waitcnt vmcnt(0)" ::: "memory")
#define WAIT_LGKM0 asm volatile("s_waitcnt lgkmcnt(0)" ::: "memory")
#define BAR() __builtin_amdgcn_s_barrier()

// ---------------- convert x -> bf16 ----------------
__global__ void cvt_x_k(const float* __restrict__ x, unsigned short* __restrict__ xb) {
  int i = blockIdx.x * 256 + threadIdx.x;            // over NTOK*DDIM/4
  float4 v = ((const float4*)x)[i];
  u16x4 o;
  o[0] = f2bf(v.x); o[1] = f2bf(v.y); o[2] = f2bf(v.z); o[3] = f2bf(v.w);
  ((u16x4*)xb)[i] = o;
}

// ---------------- transpose + convert weights ----------------
// src: [R][C] fp32 per expert, dst: [C][R] bf16 per expert. grid (C/64, R/64, E)
__global__ void tcvt_k(const float* __restrict__ src, unsigned short* __restrict__ dst,
                       int R, int C) {
  __shared__ unsigned short tile[64][65];
  long base = (long)blockIdx.z * R * C;
  src += base; dst += base;
  int r0 = blockIdx.y * 64, c0 = blockIdx.x * 64;
  int t = threadIdx.x;
  int rr = t >> 4, cc = (t & 15) * 4;
  for (int i = 0; i < 4; ++i) {
    float4 v = *(const float4*)&src[(long)(r0 + rr + i * 16) * C + c0 + cc];
    tile[rr + i * 16][cc + 0] = f2bf(v.x);
    tile[rr + i * 16][cc + 1] = f2bf(v.y);
    tile[rr + i * 16][cc + 2] = f2bf(v.z);
    tile[rr + i * 16][cc + 3] = f2bf(v.w);
  }
  __syncthreads();
  int dr = t >> 2, sg = (t & 3) * 16;
  u16x8 o0, o1;
  for (int i = 0; i < 8; ++i) { o0[i] = tile[sg + i][dr]; o1[i] = tile[sg + 8 + i][dr]; }
  unsigned short* dp = &dst[(long)(c0 + dr) * R + r0 + sg];
  *(u16x8*)dp = o0;
  *(u16x8*)(dp + 8) = o1;
}

// ---------------- router: logits, softmax, top2 ----------------
__global__ void router_k(const float* __restrict__ x, const float* __restrict__ Wr,
                         int* __restrict__ meta, int2* __restrict__ tt_i,
                         float2* __restrict__ tt_w) {
  int lane = threadIdx.x & 63;
  int tok = blockIdx.x * 4 + (threadIdx.x >> 6);
  float acc[8];
#pragma unroll
  for (int e = 0; e < 8; ++e) acc[e] = 0.f;
  const float4* xr = (const float4*)(x + (long)tok * DDIM);
#pragma unroll
  for (int it = 0; it < 4; ++it) {
    float4 v = xr[it * 64 + lane];
    int d = (it * 64 + lane) * 4;
    float xv[4] = {v.x, v.y, v.z, v.w};
#pragma unroll
    for (int j = 0; j < 4; ++j) {
      const float4* wr = (const float4*)(Wr + (long)(d + j) * NEXP);
      float4 wa = wr[0], wb = wr[1];
      acc[0] += xv[j] * wa.x; acc[1] += xv[j] * wa.y;
      acc[2] += xv[j] * wa.z; acc[3] += xv[j] * wa.w;
      acc[4] += xv[j] * wb.x; acc[5] += xv[j] * wb.y;
      acc[6] += xv[j] * wb.z; acc[7] += xv[j] * wb.w;
    }
  }
#pragma unroll
  for (int e = 0; e < 8; ++e)
    for (int off = 32; off; off >>= 1) acc[e] += __shfl_xor(acc[e], off, 64);
  if (lane == 0) {
    float m = acc[0];
    for (int e = 1; e < 8; ++e) m = fmaxf(m, acc[e]);
    float p[8];
    for (int e = 0; e < 8; ++e) p[e] = __expf(acc[e] - m);
    int e0 = 0;
    for (int e = 1; e < 8; ++e) if (p[e] > p[e0]) e0 = e;      // first max (jax tie rule)
    int e1 = -1;
    for (int e = 0; e < 8; ++e) { if (e == e0) continue; if (e1 < 0 || p[e] > p[e1]) e1 = e; }
    float s = p[e0] + p[e1];
    atomicAdd(&meta[e0], 1);
    atomicAdd(&meta[e1], 1);
    tt_i[tok] = make_int2(e0, e1);
    tt_w[tok] = make_float2(p[e0] / s, p[e1] / s);
  }
}

// ---------------- prefix offsets ----------------
__global__ void offsets_k(int* meta) {
  int run = 0;
  for (int e = 0; e < NEXP; ++e) { meta[16 + e] = run; run += meta[e]; }
}

// ---------------- scatter tokens to expert slots ----------------
__global__ void scatter_k(const int2* __restrict__ tt_i, const float2* __restrict__ tt_w,
                          int* __restrict__ meta, int* __restrict__ slot_tok,
                          float* __restrict__ slot_w, int2* __restrict__ tok_slot) {
  int n = blockIdx.x * 256 + threadIdx.x;
  int2 ei = tt_i[n];
  float2 wv = tt_w[n];
  int p0 = atomicAdd(&meta[8 + ei.x], 1);
  int s0 = meta[16 + ei.x] + p0;
  slot_tok[s0] = n; slot_w[s0] = wv.x;
  int p1 = atomicAdd(&meta[8 + ei.y], 1);
  int s1 = meta[16 + ei.y] + p1;
  slot_tok[s1] = n; slot_w[s1] = wv.y;
  tok_slot[n] = make_int2(s0, s1);
}

// ---------------- GEMM1 + SwiGLU: h = silu(X@W1) * (X@W3) ----------------
// grid (FDIM/64, NTOK/128, E), block 256. Tile: 128 slots x (64 gate + 64 up).
// Double-buffered LDS, prefetch spans the barrier via counted vmcnt (T3 recipe).
__global__ __launch_bounds__(256) void gemm1_k(
    const unsigned short* __restrict__ xb, const unsigned short* __restrict__ w13t,
    const int* __restrict__ meta, const int* __restrict__ slot_tok,
    unsigned short* __restrict__ h) {
  int e = blockIdx.z;
  int n_e = meta[e];
  int m0 = blockIdx.y * 128;
  if (m0 >= n_e) return;
  int base = meta[16 + e];
  int c0 = blockIdx.x * 64;
  const unsigned short* wB = w13t + (long)e * DF2 * DDIM;

  __shared__ unsigned short Al[2][128 * 32];
  __shared__ unsigned short B1l[2][64 * 32];
  __shared__ unsigned short B2l[2][64 * 32];

  int t = threadIdx.x;
  int lane = t & 63, w = t >> 6;
  int wm = w & 1, wn = w >> 1;
  int ar0 = t >> 2, ac = (t & 3) * 8;

  int tokA0 = slot_tok[base + min(m0 + ar0, n_e - 1)];
  int tokA1 = slot_tok[base + min(m0 + 64 + ar0, n_e - 1)];
  const unsigned short* gA0 = xb + (long)tokA0 * DDIM + ac;
  const unsigned short* gA1 = xb + (long)tokA1 * DDIM + ac;
  const unsigned short* gB1 = wB + (long)(c0 + ar0) * DDIM + ac;
  const unsigned short* gB2 = gB1 + (long)FDIM * DDIM;

  f32x4 accg[4][2], accu[4][2];
#pragma unroll
  for (int mi = 0; mi < 4; ++mi)
#pragma unroll
    for (int ni = 0; ni < 2; ++ni) {
      accg[mi][ni] = (f32x4){0.f, 0.f, 0.f, 0.f};
      accu[mi][ni] = (f32x4){0.f, 0.f, 0.f, 0.f};
    }

  int q8 = (lane >> 4) * 8;
  int arow = lane & 15;
  bf16x8 a[4], b1[2], b2[2];

#define G1_STAGE(bb, k0)                                      \
  do {                                                        \
    gl_lds16(gA0 + (k0), &Al[bb][(size_t)t * 8]);             \
    gl_lds16(gA1 + (k0), &Al[bb][(size_t)(t + 256) * 8]);     \
    gl_lds16(gB1 + (k0), &B1l[bb][(size_t)t * 8]);            \
    gl_lds16(gB2 + (k0), &B2l[bb][(size_t)t * 8]);            \
  } while (0)

#define G1_FRAGS(bb)                                                          \
  do {                                                                        \
    const unsigned short* As = Al[bb];                                        \
    const unsigned short* B1s = B1l[bb];                                      \
    const unsigned short* B2s = B2l[bb];                                      \
    _Pragma("unroll")                                                         \
    for (int mi = 0; mi < 4; ++mi)                                            \
      a[mi] = *(const bf16x8*)&As[(wm * 64 + mi * 16 + arow) * 32 + q8];      \
    _Pragma("unroll")                                                         \
    for (int ni = 0; ni < 2; ++ni) {                                          \
      b1[ni] = *(const bf16x8*)&B1s[(wn * 32 + ni * 16 + arow) * 32 + q8];    \
      b2[ni] = *(const bf16x8*)&B2s[(wn * 32 + ni * 16 + arow) * 32 + q8];    \
    }                                                                         \
  } while (0)

#define G1_MFMA()                                                                                    \
  _Pragma("unroll")                                                                                  \
  for (int mi = 0; mi < 4; ++mi)                                                                     \
    _Pragma("unroll")                                                                                \
    for (int ni = 0; ni < 2; ++ni) {                                                                 \
      accg[mi][ni] = __builtin_amdgcn_mfma_f32_16x16x32_bf16(a[mi], b1[ni], accg[mi][ni], 0, 0, 0);  \
      accu[mi][ni] = __builtin_amdgcn_mfma_f32_16x16x32_bf16(a[mi], b2[ni], accu[mi][ni], 0, 0, 0);  \
    }

  G1_STAGE(0, 0);
  int cur = 0;
#pragma unroll 1
  for (int k = 1; k < DDIM / 32; ++k) {
    G1_STAGE(cur ^ 1, k * 32);
    WAIT_VM4;            // oldest 4 (tile k-1, buf cur) complete; 4 in flight
    BAR();               // tile cur ready for all waves
    G1_FRAGS(cur);
    WAIT_LGKM0;          // my ds_reads landed in regs
    BAR();               // all waves done reading buf cur -> safe to overwrite next iter
    G1_MFMA();
    cur ^= 1;
  }
  WAIT_VM0;
  BAR();
  G1_FRAGS(cur);
  G1_MFMA();

  // epilogue: SwiGLU -> h (bf16). C/D: col=lane&15, row=quad*4+reg
  int quad = lane >> 4;
  int col0 = c0 + wn * 32 + (lane & 15);
#pragma unroll
  for (int mi = 0; mi < 4; ++mi)
#pragma unroll
    for (int r = 0; r < 4; ++r) {
      int m = m0 + wm * 64 + mi * 16 + quad * 4 + r;
      if (m < n_e) {
        unsigned short* hp = &h[(long)(base + m) * FDIM + col0];
#pragma unroll
        for (int ni = 0; ni < 2; ++ni) {
          float g = accg[mi][ni][r], u = accu[mi][ni][r];
          float hv = (g / (1.f + __expf(-g))) * u;
          hp[ni * 16] = f2bf(hv);
        }
      }
    }
}

// ---------------- GEMM2: y[slot] = w * (h @ W2)  (no atomics) ----------------
// grid (DDIM/128, NTOK/128, E), block 256. Tile 128x128.
__global__ __launch_bounds__(256) void gemm2_k(
    const unsigned short* __restrict__ h, const unsigned short* __restrict__ w2t,
    const int* __restrict__ meta, const float* __restrict__ slot_w,
    float* __restrict__ y) {
  int e = blockIdx.z;
  int n_e = meta[e];
  int m0 = blockIdx.y * 128;
  if (m0 >= n_e) return;
  int base = meta[16 + e];
  int n0 = blockIdx.x * 128;
  const unsigned short* wB = w2t + (long)e * DDIM * FDIM;

  __shared__ unsigned short Al[2][128 * 32];
  __shared__ unsigned short Bl[2][128 * 32];

  int t = threadIdx.x;
  int lane = t & 63, w = t >> 6;
  int wm = w & 1, wn = w >> 1;
  int ar0 = t >> 2, ac = (t & 3) * 8;

  int rA0 = base + min(m0 + ar0, n_e - 1);
  int rA1 = base + min(m0 + 64 + ar0, n_e - 1);
  const unsigned short* gA0 = h + (long)rA0 * FDIM + ac;
  const unsigned short* gA1 = h + (long)rA1 * FDIM + ac;
  const unsigned short* gB0 = wB + (long)(n0 + ar0) * FDIM + ac;
  const unsigned short* gB1 = gB0 + (long)64 * FDIM;

  f32x4 acc[4][4];
#pragma unroll
  for (int mi = 0; mi < 4; ++mi)
#pragma unroll
    for (int ni = 0; ni < 4; ++ni) acc[mi][ni] = (f32x4){0.f, 0.f, 0.f, 0.f};

  int q8 = (lane >> 4) * 8;
  int arow = lane & 15;
  bf16x8 a[4], b[4];

#define G2_STAGE(bb, k0)                                      \
  do {                                                        \
    gl_lds16(gA0 + (k0), &Al[bb][(size_t)t * 8]);             \
    gl_lds16(gA1 + (k0), &Al[bb][(size_t)(t + 256) * 8]);     \
    gl_lds16(gB0 + (k0), &Bl[bb][(size_t)t * 8]);             \
    gl_lds16(gB1 + (k0), &Bl[bb][(size_t)(t + 256) * 8]);     \
  } while (0)

#define G2_FRAGS(bb)                                                        \
  do {                                                                      \
    const unsigned short* As = Al[bb];                                      \
    const unsigned short* Bs = Bl[bb];                                      \
    _Pragma("unroll")                                                       \
    for (int mi = 0; mi < 4; ++mi)                                          \
      a[mi] = *(const bf16x8*)&As[(wm * 64 + mi * 16 + arow) * 32 + q8];    \
    _Pragma("unroll")                                                       \
    for (int ni = 0; ni < 4; ++ni)                                          \
      b[ni] = *(const bf16x8*)&Bs[(wn * 64 + ni * 16 + arow) * 32 + q8];    \
  } while (0)

#define G2_MFMA()                                                                                \
  _Pragma("unroll")                                                                              \
  for (int mi = 0; mi < 4; ++mi)                                                                 \
    _Pragma("unroll")                                                                            \
    for (int ni = 0; ni < 4; ++ni)                                                               \
      acc[mi][ni] = __builtin_amdgcn_mfma_f32_16x16x32_bf16(a[mi], b[ni], acc[mi][ni], 0, 0, 0);

  G2_STAGE(0, 0);
  int cur = 0;
#pragma unroll 1
  for (int k = 1; k < FDIM / 32; ++k) {
    G2_STAGE(cur ^ 1, k * 32);
    WAIT_VM4;
    BAR();
    G2_FRAGS(cur);
    WAIT_LGKM0;
    BAR();
    G2_MFMA();
    cur ^= 1;
  }
  WAIT_VM0;
  BAR();
  G2_FRAGS(cur);
  G2_MFMA();

  int quad = lane >> 4;
#pragma unroll
  for (int mi = 0; mi < 4; ++mi)
#pragma unroll
    for (int r = 0; r < 4; ++r) {
      int m = m0 + wm * 64 + mi * 16 + quad * 4 + r;
      if (m < n_e) {
        float wgt = slot_w[base + m];
        float* yp = y + (long)(base + m) * DDIM + n0 + wn * 64 + (lane & 15);
#pragma unroll
        for (int ni = 0; ni < 4; ++ni) yp[ni * 16] = wgt * acc[mi][ni][r];
      }
    }
}

// ---------------- combine: out[tok] = y[slot0] + y[slot1] ----------------
__global__ void combine_k(const float* __restrict__ y, const int2* __restrict__ tok_slot,
                          float* __restrict__ out) {
  int tok = blockIdx.x * 4 + (threadIdx.x >> 6);
  int lane = threadIdx.x & 63;
  int2 s = tok_slot[tok];
  const float4* y0 = (const float4*)(y + (long)s.x * DDIM);
  const float4* y1 = (const float4*)(y + (long)s.y * DDIM);
  float4* o = (float4*)(out + (long)tok * DDIM);
#pragma unroll
  for (int i = 0; i < 4; ++i) {
    float4 u = y0[i * 64 + lane], v = y1[i * 64 + lane];
    o[i * 64 + lane] = make_float4(u.x + v.x, u.y + v.y, u.z + v.z, u.w + v.w);
  }
}

extern "C" void kernel_launch(void* const* d_in, const int* in_sizes, int n_in,
                              void* d_out, int out_size, void* d_ws, size_t ws_size,
                              hipStream_t stream) {
  const float* x   = (const float*)d_in[0];
  const float* W13 = (const float*)d_in[1];
  const float* W2  = (const float*)d_in[2];
  const float* Wr  = (const float*)d_in[3];
  float* out = (float*)d_out;
  char* ws = (char*)d_ws;

  unsigned short* xb   = (unsigned short*)(ws + XB_OFF);
  unsigned short* w13t = (unsigned short*)(ws + W13T_OFF);
  unsigned short* w2t  = (unsigned short*)(ws + W2T_OFF);
  unsigned short* hbuf = (unsigned short*)(ws + H_OFF);
  int*    slot_tok = (int*)(ws + ST_OFF);
  float*  slot_w   = (float*)(ws + SW_OFF);
  int2*   tt_i     = (int2*)(ws + TTI_OFF);
  float2* tt_w     = (float2*)(ws + TTW_OFF);
  int*    meta     = (int*)(ws + META_OFF);
  int2*   tok_slot = (int2*)(ws + TS_OFF);
  float*  ybuf     = (float*)(ws + W13T_OFF);  // aliases W13^T (dead after gemm1)

  hipMemsetAsync(meta, 0, 128, stream);

  cvt_x_k<<<NTOK * DDIM / 4 / 256, 256, 0, stream>>>(x, xb);
  tcvt_k<<<dim3(DF2 / 64, DDIM / 64, NEXP), 256, 0, stream>>>(W13, w13t, DDIM, DF2);
  tcvt_k<<<dim3(DDIM / 64, FDIM / 64, NEXP), 256, 0, stream>>>(W2, w2t, FDIM, DDIM);
  router_k<<<NTOK / 4, 256, 0, stream>>>(x, Wr, meta, tt_i, tt_w);
  offsets_k<<<1, 1, 0, stream>>>(meta);
  scatter_k<<<NTOK / 256, 256, 0, stream>>>(tt_i, tt_w, meta, slot_tok, slot_w, tok_slot);
  gemm1_k<<<dim3(FDIM / 64, NTOK / 128, NEXP), 256, 0, stream>>>(xb, w13t, meta, slot_tok, hbuf);
  gemm2_k<<<dim3(DDIM / 128, NTOK / 128, NEXP), 256, 0, stream>>>(hbuf, w2t, meta, slot_w, ybuf);
  combine_k<<<NTOK / 4, 256, 0, stream>>>(ybuf, tok_slot, out);
}

// Round 3
// 1113.190 us; speedup vs baseline: 1.0084x; 1.0084x over previous
//
#include <hip/hip_runtime.h>
#include <stdint.h>

#define NTOK 8192
#define DDIM 1024
#define FDIM 2752
#define NEXP 8
#define DF2  5504   // 2F
#define NSLOT 16384 // NTOK * TOPK
#define NT1 16      // gemm1 K-tiles: 1024/64
#define NT2 43      // gemm2 K-tiles: 2752/64

typedef __attribute__((ext_vector_type(8))) short bf16x8;
typedef __attribute__((ext_vector_type(4))) float f32x4;
typedef __attribute__((ext_vector_type(4))) unsigned short u16x4;
typedef __attribute__((ext_vector_type(8))) unsigned short u16x8;

// ---- workspace layout (bytes) ----
constexpr size_t XB_OFF   = 0;                                   // x bf16 [NTOK][DDIM]
constexpr size_t XB_SZ    = (size_t)NTOK * DDIM * 2;
constexpr size_t W13T_OFF = XB_OFF + XB_SZ;                      // W13^T bf16 [E][2F][D]
constexpr size_t W13T_SZ  = (size_t)NEXP * DF2 * DDIM * 2;
constexpr size_t W2T_OFF  = W13T_OFF + W13T_SZ;                  // W2^T bf16 [E][D][F]
constexpr size_t W2T_SZ   = (size_t)NEXP * DDIM * FDIM * 2;
constexpr size_t H_OFF    = W2T_OFF + W2T_SZ;                    // h bf16 [NSLOT][F]
constexpr size_t H_SZ     = (size_t)NSLOT * FDIM * 2;
constexpr size_t ST_OFF   = H_OFF + H_SZ;                        // slot_token i32
constexpr size_t SW_OFF   = ST_OFF + (size_t)NSLOT * 4;          // slot_weight f32
constexpr size_t TTI_OFF  = SW_OFF + (size_t)NSLOT * 4;          // per-token top2 idx (int2)
constexpr size_t TTW_OFF  = TTI_OFF + (size_t)NTOK * 8;          // per-token top2 w (float2)
constexpr size_t META_OFF = TTW_OFF + (size_t)NTOK * 8;          // cnt[8], cnt2[8], off[8]
constexpr size_t TS_OFF   = META_OFF + 256;                      // token -> slots (int2)
// y fp32 [NSLOT][DDIM] (64MB) aliases W13T region (90MB): W13^T dead after gemm1.

__device__ __forceinline__ unsigned short f2bf(float f) {
  unsigned u = __float_as_uint(f);
  u += 0x7FFFu + ((u >> 16) & 1u);     // RNE
  return (unsigned short)(u >> 16);
}

__device__ __forceinline__ void gl_lds16(const void* g, void* l) {
  __builtin_amdgcn_global_load_lds(
      (const __attribute__((address_space(1))) unsigned int*)g,
      (__attribute__((address_space(3))) unsigned int*)l, 16, 0, 0);
}

#define BARF()  do { asm volatile("" ::: "memory"); __builtin_amdgcn_s_barrier(); asm volatile("" ::: "memory"); } while (0)
#define LGKM0   asm volatile("s_waitcnt lgkmcnt(0)" ::: "memory")
#define GATE6   asm volatile("s_waitcnt vmcnt(6)" ::: "memory")
#define GATE4   asm volatile("s_waitcnt vmcnt(4)" ::: "memory")
#define VM0     asm volatile("s_waitcnt vmcnt(0)" ::: "memory")
#define PRIO1   __builtin_amdgcn_s_setprio(1)
#define PRIO0   __builtin_amdgcn_s_setprio(0)
#define MFMA16(aa, bb, cc) cc = __builtin_amdgcn_mfma_f32_16x16x32_bf16(aa, bb, cc, 0, 0, 0)

// stage one 16KB half-tile (128 rows x 64 k): 512 threads x 2 gl_lds x 16B.
// koff pre-clamped by caller; invalid stages re-read k=0 into regions never read again.
#define STG(dstbase, parr, koff)                        \
  do {                                                  \
    gl_lds16(parr[0] + (koff), (dstbase) + sdst);       \
    gl_lds16(parr[1] + (koff), (dstbase) + sdst + 512); \
  } while (0)

// ---------------- convert x -> bf16 ----------------
__global__ void cvt_x_k(const float* __restrict__ x, unsigned short* __restrict__ xb) {
  int i = blockIdx.x * 256 + threadIdx.x;
  float4 v = ((const float4*)x)[i];
  u16x4 o;
  o[0] = f2bf(v.x); o[1] = f2bf(v.y); o[2] = f2bf(v.z); o[3] = f2bf(v.w);
  ((u16x4*)xb)[i] = o;
}

// ---------------- transpose + convert weights ----------------
__global__ void tcvt_k(const float* __restrict__ src, unsigned short* __restrict__ dst,
                       int R, int C) {
  __shared__ unsigned short tile[64][65];
  long base = (long)blockIdx.z * R * C;
  src += base; dst += base;
  int r0 = blockIdx.y * 64, c0 = blockIdx.x * 64;
  int t = threadIdx.x;
  int rr = t >> 4, cc = (t & 15) * 4;
  for (int i = 0; i < 4; ++i) {
    float4 v = *(const float4*)&src[(long)(r0 + rr + i * 16) * C + c0 + cc];
    tile[rr + i * 16][cc + 0] = f2bf(v.x);
    tile[rr + i * 16][cc + 1] = f2bf(v.y);
    tile[rr + i * 16][cc + 2] = f2bf(v.z);
    tile[rr + i * 16][cc + 3] = f2bf(v.w);
  }
  __syncthreads();
  int dr = t >> 2, sg = (t & 3) * 16;
  u16x8 o0, o1;
  for (int i = 0; i < 8; ++i) { o0[i] = tile[sg + i][dr]; o1[i] = tile[sg + 8 + i][dr]; }
  unsigned short* dp = &dst[(long)(c0 + dr) * R + r0 + sg];
  *(u16x8*)dp = o0;
  *(u16x8*)(dp + 8) = o1;
}

// ---------------- router ----------------
__global__ void router_k(const float* __restrict__ x, const float* __restrict__ Wr,
                         int* __restrict__ meta, int2* __restrict__ tt_i,
                         float2* __restrict__ tt_w) {
  int lane = threadIdx.x & 63;
  int tok = blockIdx.x * 4 + (threadIdx.x >> 6);
  float acc[8];
#pragma unroll
  for (int e = 0; e < 8; ++e) acc[e] = 0.f;
  const float4* xr = (const float4*)(x + (long)tok * DDIM);
#pragma unroll
  for (int it = 0; it < 4; ++it) {
    float4 v = xr[it * 64 + lane];
    int d = (it * 64 + lane) * 4;
    float xv[4] = {v.x, v.y, v.z, v.w};
#pragma unroll
    for (int j = 0; j < 4; ++j) {
      const float4* wr = (const float4*)(Wr + (long)(d + j) * NEXP);
      float4 wa = wr[0], wb = wr[1];
      acc[0] += xv[j] * wa.x; acc[1] += xv[j] * wa.y;
      acc[2] += xv[j] * wa.z; acc[3] += xv[j] * wa.w;
      acc[4] += xv[j] * wb.x; acc[5] += xv[j] * wb.y;
      acc[6] += xv[j] * wb.z; acc[7] += xv[j] * wb.w;
    }
  }
#pragma unroll
  for (int e = 0; e < 8; ++e)
    for (int off = 32; off; off >>= 1) acc[e] += __shfl_xor(acc[e], off, 64);
  if (lane == 0) {
    float m = acc[0];
    for (int e = 1; e < 8; ++e) m = fmaxf(m, acc[e]);
    float p[8];
    for (int e = 0; e < 8; ++e) p[e] = __expf(acc[e] - m);
    int e0 = 0;
    for (int e = 1; e < 8; ++e) if (p[e] > p[e0]) e0 = e;
    int e1 = -1;
    for (int e = 0; e < 8; ++e) { if (e == e0) continue; if (e1 < 0 || p[e] > p[e1]) e1 = e; }
    float s = p[e0] + p[e1];
    atomicAdd(&meta[e0], 1);
    atomicAdd(&meta[e1], 1);
    tt_i[tok] = make_int2(e0, e1);
    tt_w[tok] = make_float2(p[e0] / s, p[e1] / s);
  }
}

__global__ void offsets_k(int* meta) {
  int run = 0;
  for (int e = 0; e < NEXP; ++e) { meta[16 + e] = run; run += meta[e]; }
}

__global__ void scatter_k(const int2* __restrict__ tt_i, const float2* __restrict__ tt_w,
                          int* __restrict__ meta, int* __restrict__ slot_tok,
                          float* __restrict__ slot_w, int2* __restrict__ tok_slot) {
  int n = blockIdx.x * 256 + threadIdx.x;
  int2 ei = tt_i[n];
  float2 wv = tt_w[n];
  int p0 = atomicAdd(&meta[8 + ei.x], 1);
  int s0 = meta[16 + ei.x] + p0;
  slot_tok[s0] = n; slot_w[s0] = wv.x;
  int p1 = atomicAdd(&meta[8 + ei.y], 1);
  int s1 = meta[16 + ei.y] + p1;
  slot_tok[s1] = n; slot_w[s1] = wv.y;
  tok_slot[n] = make_int2(s0, s1);
}

// ---------------- GEMM1 + SwiGLU (4-phase/K-tile pipeline, 256x(128g+128u), BK=64) ----
// 8 waves (2Mx4N), 128KB LDS dbuf, st_16x32 swizzle. Stage cadence per iter U:
//   p0:(U+1).A0  p1:(U+1).A1  p2:(U+1).B1  p3:(U+2).B0
// Gates (before the phase-end barrier; FIFO-derived):
//   p0: GATE4 drains (U).B1 (read at p1)
//   p2: GATE6 drains (U+1).B0 (smoothing)
//   p3: GATE4 drains (U+1).A0/A1 (read at U+1.p0); leaves {(U+1).B1,(U+2).B0}=4
// Every stage targets a region whose readers drained (LGKM0) before the prior barrier.
__global__ __launch_bounds__(512, 2) void gemm1_k(
    const unsigned short* __restrict__ xb, const unsigned short* __restrict__ w13t,
    const int* __restrict__ meta, const int* __restrict__ slot_tok,
    unsigned short* __restrict__ h) {
  int e = blockIdx.z;
  int n_e = meta[e];
  int m0 = blockIdx.y * 256;
  if (m0 >= n_e) return;
  int base = meta[16 + e];
  int c0 = blockIdx.x * 128;
  const unsigned short* wB = w13t + (long)e * DF2 * DDIM;

  __shared__ unsigned short Ab[2][2][8192];  // [buf][half][128 x 64], swizzled
  __shared__ unsigned short Bb[2][2][8192];  // half0 = gate rows, half1 = up rows

  int t = threadIdx.x;
  int lane = t & 63, w = t >> 6;
  int wm = w >> 2, wn = w & 3;
  int fr = lane & 15;

  // staging: linear LDS dest (wave-uniform base + lane*16B), swizzled global source
  int rj = w * 16 + (lane >> 3);                       // j=0 row in half (j adds 8)
  int kc = ((lane & 7) ^ ((lane >> 4) & 2)) * 8;       // source k-chunk (elements)
  int sdst = w * 1024 + lane * 8;                      // short offset in half (j adds 512)

  const unsigned short* pA[2][2];
  const unsigned short* pB[2][2];
#pragma unroll
  for (int hh = 0; hh < 2; ++hh)
#pragma unroll
    for (int j = 0; j < 2; ++j) {
      int tr = hh * 128 + rj + j * 8;
      int tok = slot_tok[base + min(m0 + tr, n_e - 1)];
      pA[hh][j] = xb + (long)tok * DDIM + kc;
      int wr = (tr < 128) ? min(c0 + tr, FDIM - 1) : FDIM + min(c0 + tr - 128, FDIM - 1);
      pB[hh][j] = wB + (long)wr * DDIM + kc;
    }

  // read-side swizzle: chunk = (lane>>4) ^ ((fr>>2)&1)*2  (same involution)
  int qp = ((lane >> 4) ^ ((lane >> 2) & 1) * 2) * 8;
  int abase = fr * 64 + qp;
  int bbase = wn * 2048 + fr * 64 + qp;

  f32x4 acc[8][4];
#pragma unroll
  for (int mi = 0; mi < 8; ++mi)
#pragma unroll
    for (int n = 0; n < 4; ++n) acc[mi][n] = (f32x4){0.f, 0.f, 0.f, 0.f};
  bf16x8 a[8], b0, b1;

  // prologue: 0.A0, 0.A1, 0.B0, 0.B1, 1.B0 (10 loads); gate to {0.B1,1.B0}=4
  STG(&Ab[0][0][0], pA[0], 0);
  STG(&Ab[0][1][0], pA[1], 0);
  STG(&Bb[0][0][0], pB[0], 0);
  STG(&Bb[0][1][0], pB[1], 0);
  STG(&Bb[1][0][0], pB[0], (1 < NT1) ? 64 : 0);
  GATE4;
  BARF();

#pragma unroll 1
  for (int U = 0; U < NT1; ++U) {
    int cur = U & 1, nxt = cur ^ 1;
    const unsigned short* Ac = &Ab[cur][wm][0];
    const unsigned short* B0c = &Bb[cur][0][0];
    const unsigned short* B1c = &Bb[cur][1][0];
    int k1 = ((U + 1) < NT1) ? (U + 1) * 64 : 0;
    int k2 = ((U + 2) < NT1) ? (U + 2) * 64 : 0;
    // ---- p0: ks=0, n={0,1} (gate) ----
#pragma unroll
    for (int mi = 0; mi < 8; ++mi) a[mi] = *(const bf16x8*)&Ac[mi * 1024 + abase];
    b0 = *(const bf16x8*)&B0c[bbase];
    b1 = *(const bf16x8*)&B0c[1024 + bbase];
    STG(&Ab[nxt][0][0], pA[0], k1);
    BARF(); LGKM0;
    PRIO1;
#pragma unroll
    for (int mi = 0; mi < 8; ++mi) { MFMA16(a[mi], b0, acc[mi][0]); MFMA16(a[mi], b1, acc[mi][1]); }
    PRIO0;
    GATE4;   // drains (U).B1 -> safe to read at p1 after this barrier
    BARF();
    // ---- p1: ks=0, n={2,3} (up) ----
    b0 = *(const bf16x8*)&B1c[bbase];
    b1 = *(const bf16x8*)&B1c[1024 + bbase];
    STG(&Ab[nxt][1][0], pA[1], k1);
    BARF(); LGKM0;
    PRIO1;
#pragma unroll
    for (int mi = 0; mi < 8; ++mi) { MFMA16(a[mi], b0, acc[mi][2]); MFMA16(a[mi], b1, acc[mi][3]); }
    PRIO0;
    BARF();
    // ---- p2: ks=1, n={0,1} ----
#pragma unroll
    for (int mi = 0; mi < 8; ++mi) a[mi] = *(const bf16x8*)&Ac[mi * 1024 + 32 + abase];
    b0 = *(const bf16x8*)&B0c[32 + bbase];
    b1 = *(const bf16x8*)&B0c[1024 + 32 + bbase];
    STG(&Bb[nxt][1][0], pB[1], k1);
    BARF(); LGKM0;
    PRIO1;
#pragma unroll
    for (int mi = 0; mi < 8; ++mi) { MFMA16(a[mi], b0, acc[mi][0]); MFMA16(a[mi], b1, acc[mi][1]); }
    PRIO0;
    GATE6;   // smoothing drain of (U+1).B0
    BARF();
    // ---- p3: ks=1, n={2,3} ----
    b0 = *(const bf16x8*)&B1c[32 + bbase];
    b1 = *(const bf16x8*)&B1c[1024 + 32 + bbase];
    STG(&Bb[cur][0][0], pB[0], k2);   // B-half0 of cur freed after p2's drain+barrier
    BARF(); LGKM0;
    PRIO1;
#pragma unroll
    for (int mi = 0; mi < 8; ++mi) { MFMA16(a[mi], b0, acc[mi][2]); MFMA16(a[mi], b1, acc[mi][3]); }
    PRIO0;
    GATE4;   // drains (U+1).A0/A1 -> readable at U+1.p0
    BARF();
  }
  VM0;  // drain tail stages

  // epilogue: SwiGLU -> h. C/D: col=lane&15, row=(lane>>4)*4+reg
  int quad = lane >> 4;
#pragma unroll
  for (int mi = 0; mi < 8; ++mi)
#pragma unroll
    for (int r = 0; r < 4; ++r) {
      int m = m0 + wm * 128 + mi * 16 + quad * 4 + r;
      if (m < n_e) {
        unsigned short* hp = &h[(long)(base + m) * FDIM];
#pragma unroll
        for (int n = 0; n < 2; ++n) {
          int col = c0 + wn * 32 + n * 16 + fr;
          if (col < FDIM) {
            float g = acc[mi][n][r], u = acc[mi][n + 2][r];
            hp[col] = f2bf((g / (1.f + __expf(-g))) * u);
          }
        }
      }
    }
}

// ---------------- GEMM2: y[slot] = w * (h @ W2), same 4-phase schedule ----------------
// Tile 256 slots x 256 cols, K = 2752 = 43x64 exact. grid (4, 32, 8).
__global__ __launch_bounds__(512, 2) void gemm2_k(
    const unsigned short* __restrict__ hb, const unsigned short* __restrict__ w2t,
    const int* __restrict__ meta, const float* __restrict__ slot_w,
    float* __restrict__ y) {
  int e = blockIdx.z;
  int n_e = meta[e];
  int m0 = blockIdx.y * 256;
  if (m0 >= n_e) return;
  int base = meta[16 + e];
  int c0 = blockIdx.x * 256;
  const unsigned short* wB = w2t + (long)e * DDIM * FDIM;

  __shared__ unsigned short Ab[2][2][8192];
  __shared__ unsigned short Bb[2][2][8192];

  int t = threadIdx.x;
  int lane = t & 63, w = t >> 6;
  int wm = w >> 2, wn = w & 3;
  int fr = lane & 15;

  int rj = w * 16 + (lane >> 3);
  int kc = ((lane & 7) ^ ((lane >> 4) & 2)) * 8;
  int sdst = w * 1024 + lane * 8;

  const unsigned short* pA[2][2];
  const unsigned short* pB[2][2];
#pragma unroll
  for (int hh = 0; hh < 2; ++hh)
#pragma unroll
    for (int j = 0; j < 2; ++j) {
      int tr = hh * 128 + rj + j * 8;
      int srow = base + min(m0 + tr, n_e - 1);
      pA[hh][j] = hb + (long)srow * FDIM + kc;
      pB[hh][j] = wB + (long)(c0 + tr) * FDIM + kc;
    }

  int qp = ((lane >> 4) ^ ((lane >> 2) & 1) * 2) * 8;
  int abase = fr * 64 + qp;
  int bbase = wn * 2048 + fr * 64 + qp;

  f32x4 acc[8][4];
#pragma unroll
  for (int mi = 0; mi < 8; ++mi)
#pragma unroll
    for (int n = 0; n < 4; ++n) acc[mi][n] = (f32x4){0.f, 0.f, 0.f, 0.f};
  bf16x8 a[8], b0, b1;

  STG(&Ab[0][0][0], pA[0], 0);
  STG(&Ab[0][1][0], pA[1], 0);
  STG(&Bb[0][0][0], pB[0], 0);
  STG(&Bb[0][1][0], pB[1], 0);
  STG(&Bb[1][0][0], pB[0], (1 < NT2) ? 64 : 0);
  GATE4;
  BARF();

#pragma unroll 1
  for (int U = 0; U < NT2; ++U) {
    int cur = U & 1, nxt = cur ^ 1;
    const unsigned short* Ac = &Ab[cur][wm][0];
    const unsigned short* B0c = &Bb[cur][0][0];
    const unsigned short* B1c = &Bb[cur][1][0];
    int k1 = ((U + 1) < NT2) ? (U + 1) * 64 : 0;
    int k2 = ((U + 2) < NT2) ? (U + 2) * 64 : 0;
    // p0
#pragma unroll
    for (int mi = 0; mi < 8; ++mi) a[mi] = *(const bf16x8*)&Ac[mi * 1024 + abase];
    b0 = *(const bf16x8*)&B0c[bbase];
    b1 = *(const bf16x8*)&B0c[1024 + bbase];
    STG(&Ab[nxt][0][0], pA[0], k1);
    BARF(); LGKM0;
    PRIO1;
#pragma unroll
    for (int mi = 0; mi < 8; ++mi) { MFMA16(a[mi], b0, acc[mi][0]); MFMA16(a[mi], b1, acc[mi][1]); }
    PRIO0;
    GATE4;
    BARF();
    // p1
    b0 = *(const bf16x8*)&B1c[bbase];
    b1 = *(const bf16x8*)&B1c[1024 + bbase];
    STG(&Ab[nxt][1][0], pA[1], k1);
    BARF(); LGKM0;
    PRIO1;
#pragma unroll
    for (int mi = 0; mi < 8; ++mi) { MFMA16(a[mi], b0, acc[mi][2]); MFMA16(a[mi], b1, acc[mi][3]); }
    PRIO0;
    BARF();
    // p2
#pragma unroll
    for (int mi = 0; mi < 8; ++mi) a[mi] = *(const bf16x8*)&Ac[mi * 1024 + 32 + abase];
    b0 = *(const bf16x8*)&B0c[32 + bbase];
    b1 = *(const bf16x8*)&B0c[1024 + 32 + bbase];
    STG(&Bb[nxt][1][0], pB[1], k1);
    BARF(); LGKM0;
    PRIO1;
#pragma unroll
    for (int mi = 0; mi < 8; ++mi) { MFMA16(a[mi], b0, acc[mi][0]); MFMA16(a[mi], b1, acc[mi][1]); }
    PRIO0;
    GATE6;
    BARF();
    // p3
    b0 = *(const bf16x8*)&B1c[32 + bbase];
    b1 = *(const bf16x8*)&B1c[1024 + 32 + bbase];
    STG(&Bb[cur][0][0], pB[0], k2);
    BARF(); LGKM0;
    PRIO1;
#pragma unroll
    for (int mi = 0; mi < 8; ++mi) { MFMA16(a[mi], b0, acc[mi][2]); MFMA16(a[mi], b1, acc[mi][3]); }
    PRIO0;
    GATE4;
    BARF();
  }
  VM0;

  int quad = lane >> 4;
#pragma unroll
  for (int mi = 0; mi < 8; ++mi)
#pragma unroll
    for (int r = 0; r < 4; ++r) {
      int m = m0 + wm * 128 + mi * 16 + quad * 4 + r;
      if (m < n_e) {
        float wgt = slot_w[base + m];
        float* yp = y + (long)(base + m) * DDIM;
#pragma unroll
        for (int n = 0; n < 4; ++n) {
          int col = c0 + (n >> 1) * 128 + wn * 32 + (n & 1) * 16 + fr;
          yp[col] = wgt * acc[mi][n][r];
        }
      }
    }
}

// ---------------- combine: out[tok] = y[slot0] + y[slot1] ----------------
__global__ void combine_k(const float* __restrict__ y, const int2* __restrict__ tok_slot,
                          float* __restrict__ out) {
  int tok = blockIdx.x * 4 + (threadIdx.x >> 6);
  int lane = threadIdx.x & 63;
  int2 s = tok_slot[tok];
  const float4* y0 = (const float4*)(y + (long)s.x * DDIM);
  const float4* y1 = (const float4*)(y + (long)s.y * DDIM);
  float4* o = (float4*)(out + (long)tok * DDIM);
#pragma unroll
  for (int i = 0; i < 4; ++i) {
    float4 u = y0[i * 64 + lane], v = y1[i * 64 + lane];
    o[i * 64 + lane] = make_float4(u.x + v.x, u.y + v.y, u.z + v.z, u.w + v.w);
  }
}

extern "C" void kernel_launch(void* const* d_in, const int* in_sizes, int n_in,
                              void* d_out, int out_size, void* d_ws, size_t ws_size,
                              hipStream_t stream) {
  const float* x   = (const float*)d_in[0];
  const float* W13 = (const float*)d_in[1];
  const float* W2  = (const float*)d_in[2];
  const float* Wr  = (const float*)d_in[3];
  float* out = (float*)d_out;
  char* ws = (char*)d_ws;

  unsigned short* xb   = (unsigned short*)(ws + XB_OFF);
  unsigned short* w13t = (unsigned short*)(ws + W13T_OFF);
  unsigned short* w2t  = (unsigned short*)(ws + W2T_OFF);
  unsigned short* hbuf = (unsigned short*)(ws + H_OFF);
  int*    slot_tok = (int*)(ws + ST_OFF);
  float*  slot_w   = (float*)(ws + SW_OFF);
  int2*   tt_i     = (int2*)(ws + TTI_OFF);
  float2* tt_w     = (float2*)(ws + TTW_OFF);
  int*    meta     = (int*)(ws + META_OFF);
  int2*   tok_slot = (int2*)(ws + TS_OFF);
  float*  ybuf     = (float*)(ws + W13T_OFF);  // aliases W13^T (dead after gemm1)

  hipMemsetAsync(meta, 0, 128, stream);

  cvt_x_k<<<NTOK * DDIM / 4 / 256, 256, 0, stream>>>(x, xb);
  tcvt_k<<<dim3(DF2 / 64, DDIM / 64, NEXP), 256, 0, stream>>>(W13, w13t, DDIM, DF2);
  tcvt_k<<<dim3(DDIM / 64, FDIM / 64, NEXP), 256, 0, stream>>>(W2, w2t, FDIM, DDIM);
  router_k<<<NTOK / 4, 256, 0, stream>>>(x, Wr, meta, tt_i, tt_w);
  offsets_k<<<1, 1, 0, stream>>>(meta);
  scatter_k<<<NTOK / 256, 256, 0, stream>>>(tt_i, tt_w, meta, slot_tok, slot_w, tok_slot);
  gemm1_k<<<dim3(FDIM / 128 + 1, NTOK / 256, NEXP), 512, 0, stream>>>(xb, w13t, meta, slot_tok, hbuf);
  gemm2_k<<<dim3(DDIM / 256, NTOK / 256, NEXP), 512, 0, stream>>>(hbuf, w2t, meta, slot_w, ybuf);
  combine_k<<<NTOK / 4, 256, 0, stream>>>(ybuf, tok_slot, out);
}

// Round 4
// 1064.416 us; speedup vs baseline: 1.0546x; 1.0458x over previous
//
#include <hip/hip_runtime.h>
#include <stdint.h>

#define NTOK 8192
#define DDIM 1024
#define FDIM 2752
#define NEXP 8
#define DF2  5504   // 2F
#define NSLOT 16384 // NTOK * TOPK
#define NT1 16      // gemm1 K-tiles: 1024/64
#define NT2 43      // gemm2 K-tiles: 2752/64

typedef __attribute__((ext_vector_type(8))) short bf16x8;
typedef __attribute__((ext_vector_type(4))) float f32x4;
typedef __attribute__((ext_vector_type(4))) unsigned short u16x4;
typedef __attribute__((ext_vector_type(8))) unsigned short u16x8;

// ---- workspace layout (bytes) ----
constexpr size_t XB_OFF   = 0;                                   // x bf16 [NTOK][DDIM]
constexpr size_t XB_SZ    = (size_t)NTOK * DDIM * 2;
constexpr size_t W13T_OFF = XB_OFF + XB_SZ;                      // W13^T bf16 [E][2F][D]
constexpr size_t W13T_SZ  = (size_t)NEXP * DF2 * DDIM * 2;
constexpr size_t W2T_OFF  = W13T_OFF + W13T_SZ;                  // W2^T bf16 [E][D][F]
constexpr size_t W2T_SZ   = (size_t)NEXP * DDIM * FDIM * 2;
constexpr size_t H_OFF    = W2T_OFF + W2T_SZ;                    // h bf16 [NSLOT][F]
constexpr size_t H_SZ     = (size_t)NSLOT * FDIM * 2;
constexpr size_t ST_OFF   = H_OFF + H_SZ;                        // slot_token i32
constexpr size_t SW_OFF   = ST_OFF + (size_t)NSLOT * 4;          // slot_weight f32
constexpr size_t TTI_OFF  = SW_OFF + (size_t)NSLOT * 4;          // per-token top2 idx (int2)
constexpr size_t TTW_OFF  = TTI_OFF + (size_t)NTOK * 8;          // per-token top2 w (float2)
constexpr size_t META_OFF = TTW_OFF + (size_t)NTOK * 8;          // cnt[8], cnt2[8], off[8]
constexpr size_t TS_OFF   = META_OFF + 256;                      // token -> slots (int2)
// y fp32 [NSLOT][DDIM] (64MB) aliases W13T region (90MB): W13^T dead after gemm1.

__device__ __forceinline__ unsigned short f2bf(float f) {
  unsigned u = __float_as_uint(f);
  u += 0x7FFFu + ((u >> 16) & 1u);     // RNE
  return (unsigned short)(u >> 16);
}

__device__ __forceinline__ void gl_lds16(const void* g, void* l) {
  __builtin_amdgcn_global_load_lds(
      (const __attribute__((address_space(1))) unsigned int*)g,
      (__attribute__((address_space(3))) unsigned int*)l, 16, 0, 0);
}

#define BARF()  do { asm volatile("" ::: "memory"); __builtin_amdgcn_s_barrier(); asm volatile("" ::: "memory"); } while (0)
#define LGKM0   asm volatile("s_waitcnt lgkmcnt(0)" ::: "memory")
#define GATE2   asm volatile("s_waitcnt vmcnt(2)" ::: "memory")
#define VM0     asm volatile("s_waitcnt vmcnt(0)" ::: "memory")
#define PRIO1   __builtin_amdgcn_s_setprio(1)
#define PRIO0   __builtin_amdgcn_s_setprio(0)
#define MFMA16(aa, bb, cc) cc = __builtin_amdgcn_mfma_f32_16x16x32_bf16(aa, bb, cc, 0, 0, 0)

// Stage one half-tile (128 rows x 64 k) into [ks][128][32] layout: 2 gl_lds/wave.
// Dest is wave-linear (lane*16B within each ks block); source carries the swizzle.
#define STG(dstbase, p, koff)                               \
  do {                                                      \
    gl_lds16((p) + (koff), (dstbase) + sdst);               \
    gl_lds16((p) + (koff) + 32, (dstbase) + sdst + 4096);   \
  } while (0)

// ---------------- convert x -> bf16 ----------------
__global__ void cvt_x_k(const float* __restrict__ x, unsigned short* __restrict__ xb) {
  int i = blockIdx.x * 256 + threadIdx.x;
  float4 v = ((const float4*)x)[i];
  u16x4 o;
  o[0] = f2bf(v.x); o[1] = f2bf(v.y); o[2] = f2bf(v.z); o[3] = f2bf(v.w);
  ((u16x4*)xb)[i] = o;
}

// ---------------- transpose + convert weights ----------------
__global__ void tcvt_k(const float* __restrict__ src, unsigned short* __restrict__ dst,
                       int R, int C) {
  __shared__ unsigned short tile[64][65];
  long base = (long)blockIdx.z * R * C;
  src += base; dst += base;
  int r0 = blockIdx.y * 64, c0 = blockIdx.x * 64;
  int t = threadIdx.x;
  int rr = t >> 4, cc = (t & 15) * 4;
  for (int i = 0; i < 4; ++i) {
    float4 v = *(const float4*)&src[(long)(r0 + rr + i * 16) * C + c0 + cc];
    tile[rr + i * 16][cc + 0] = f2bf(v.x);
    tile[rr + i * 16][cc + 1] = f2bf(v.y);
    tile[rr + i * 16][cc + 2] = f2bf(v.z);
    tile[rr + i * 16][cc + 3] = f2bf(v.w);
  }
  __syncthreads();
  int dr = t >> 2, sg = (t & 3) * 16;
  u16x8 o0, o1;
  for (int i = 0; i < 8; ++i) { o0[i] = tile[sg + i][dr]; o1[i] = tile[sg + 8 + i][dr]; }
  unsigned short* dp = &dst[(long)(c0 + dr) * R + r0 + sg];
  *(u16x8*)dp = o0;
  *(u16x8*)(dp + 8) = o1;
}

// ---------------- router ----------------
__global__ void router_k(const float* __restrict__ x, const float* __restrict__ Wr,
                         int* __restrict__ meta, int2* __restrict__ tt_i,
                         float2* __restrict__ tt_w) {
  int lane = threadIdx.x & 63;
  int tok = blockIdx.x * 4 + (threadIdx.x >> 6);
  float acc[8];
#pragma unroll
  for (int e = 0; e < 8; ++e) acc[e] = 0.f;
  const float4* xr = (const float4*)(x + (long)tok * DDIM);
#pragma unroll
  for (int it = 0; it < 4; ++it) {
    float4 v = xr[it * 64 + lane];
    int d = (it * 64 + lane) * 4;
    float xv[4] = {v.x, v.y, v.z, v.w};
#pragma unroll
    for (int j = 0; j < 4; ++j) {
      const float4* wr = (const float4*)(Wr + (long)(d + j) * NEXP);
      float4 wa = wr[0], wb = wr[1];
      acc[0] += xv[j] * wa.x; acc[1] += xv[j] * wa.y;
      acc[2] += xv[j] * wa.z; acc[3] += xv[j] * wa.w;
      acc[4] += xv[j] * wb.x; acc[5] += xv[j] * wb.y;
      acc[6] += xv[j] * wb.z; acc[7] += xv[j] * wb.w;
    }
  }
#pragma unroll
  for (int e = 0; e < 8; ++e)
    for (int off = 32; off; off >>= 1) acc[e] += __shfl_xor(acc[e], off, 64);
  if (lane == 0) {
    float m = acc[0];
    for (int e = 1; e < 8; ++e) m = fmaxf(m, acc[e]);
    float p[8];
    for (int e = 0; e < 8; ++e) p[e] = __expf(acc[e] - m);
    int e0 = 0;
    for (int e = 1; e < 8; ++e) if (p[e] > p[e0]) e0 = e;
    int e1 = -1;
    for (int e = 0; e < 8; ++e) { if (e == e0) continue; if (e1 < 0 || p[e] > p[e1]) e1 = e; }
    float s = p[e0] + p[e1];
    atomicAdd(&meta[e0], 1);
    atomicAdd(&meta[e1], 1);
    tt_i[tok] = make_int2(e0, e1);
    tt_w[tok] = make_float2(p[e0] / s, p[e1] / s);
  }
}

__global__ void offsets_k(int* meta) {
  int run = 0;
  for (int e = 0; e < NEXP; ++e) { meta[16 + e] = run; run += meta[e]; }
}

__global__ void scatter_k(const int2* __restrict__ tt_i, const float2* __restrict__ tt_w,
                          int* __restrict__ meta, int* __restrict__ slot_tok,
                          float* __restrict__ slot_w, int2* __restrict__ tok_slot) {
  int n = blockIdx.x * 256 + threadIdx.x;
  int2 ei = tt_i[n];
  float2 wv = tt_w[n];
  int p0 = atomicAdd(&meta[8 + ei.x], 1);
  int s0 = meta[16 + ei.x] + p0;
  slot_tok[s0] = n; slot_w[s0] = wv.x;
  int p1 = atomicAdd(&meta[8 + ei.y], 1);
  int s1 = meta[16 + ei.y] + p1;
  slot_tok[s1] = n; slot_w[s1] = wv.y;
  tok_slot[n] = make_int2(s0, s1);
}

// ---------------- GEMM1 + SwiGLU (4-phase/K-tile, 256x(128g+128u), BK=64) ----------
// LDS per half-tile: [ks][128][32] bf16 (64-byte rows) -> bank = (row&1)*16 + chunk*4;
// chunk-XOR swz = ((row>>3)&1)*2 spreads reads over all 32 banks (conflict-free).
// Stage cadence: (U+1).A0@p0, A1@p1, B0@p2, B1@p3, all into buffer nxt.
// Gates vmcnt(2) at p0-end (drains (U).B1) and p3-end (drains (U+1).A0/A1/B0).
__global__ __launch_bounds__(512, 2) void gemm1_k(
    const unsigned short* __restrict__ xb, const unsigned short* __restrict__ w13t,
    const int* __restrict__ meta, const int* __restrict__ slot_tok,
    unsigned short* __restrict__ h) {
  int e = blockIdx.z;
  int n_e = meta[e];
  int m0 = blockIdx.y * 256;
  if (m0 >= n_e) return;
  int base = meta[16 + e];
  int c0 = blockIdx.x * 128;
  const unsigned short* wB = w13t + (long)e * DF2 * DDIM;

  __shared__ unsigned short Ab[2][2][8192];  // [buf][half][ks*4096 + row*32 + k]
  __shared__ unsigned short Bb[2][2][8192];  // half0 = gate rows, half1 = up rows

  int t = threadIdx.x;
  int lane = t & 63, w = t >> 6;
  int wm = w >> 2, wn = w & 3;
  int fr = lane & 15;

  // staging: wave covers rows w*16..w*16+15, 4 chunk-lanes per row, both ks halves
  int rj = lane >> 2;                                  // row within wave's 16-row group
  int kc = ((lane & 3) ^ ((lane >> 5) & 1) * 2) * 8;   // swizzled elem off in 32-k half
  int sdst = w * 512 + lane * 8;                       // shorts; ks adds 4096

  const unsigned short* pA[2];
  const unsigned short* pB[2];
#pragma unroll
  for (int hh = 0; hh < 2; ++hh) {
    int tr = hh * 128 + w * 16 + rj;
    int tok = slot_tok[base + min(m0 + tr, n_e - 1)];
    pA[hh] = xb + (long)tok * DDIM + kc;
    int wr = hh * FDIM + min(c0 + w * 16 + rj, FDIM - 1);
    pB[hh] = wB + (long)wr * DDIM + kc;
  }

  // read-side: chunk = (lane>>4) ^ ((fr>>3)&1)*2 (same involution, row-bit3 based)
  int qp = ((lane >> 4) ^ ((fr >> 3) & 1) * 2) * 8;
  int abase = fr * 32 + qp;                 // + mi*512 + ks*4096
  int bbase = wn * 1024 + fr * 32 + qp;     // + n*512  + ks*4096

  f32x4 acc[8][4];
#pragma unroll
  for (int mi = 0; mi < 8; ++mi)
#pragma unroll
    for (int n = 0; n < 4; ++n) acc[mi][n] = (f32x4){0.f, 0.f, 0.f, 0.f};
  bf16x8 a[8], b0, b1;

  // prologue: all of tile 0, full drain
  STG(&Ab[0][0][0], pA[0], 0);
  STG(&Ab[0][1][0], pA[1], 0);
  STG(&Bb[0][0][0], pB[0], 0);
  STG(&Bb[0][1][0], pB[1], 0);
  VM0;
  BARF();

#pragma unroll 1
  for (int U = 0; U < NT1; ++U) {
    int cur = U & 1, nxt = cur ^ 1;
    const unsigned short* Ac = &Ab[cur][wm][0];
    const unsigned short* B0c = &Bb[cur][0][0];
    const unsigned short* B1c = &Bb[cur][1][0];
    int k1 = ((U + 1) < NT1) ? (U + 1) * 64 : 0;
    // ---- p0: ks=0, B-half0 (gate) ----
#pragma unroll
    for (int mi = 0; mi < 8; ++mi) a[mi] = *(const bf16x8*)&Ac[mi * 512 + abase];
    b0 = *(const bf16x8*)&B0c[bbase];
    b1 = *(const bf16x8*)&B0c[512 + bbase];
    STG(&Ab[nxt][0][0], pA[0], k1);
    BARF(); LGKM0;
    PRIO1;
#pragma unroll
    for (int mi = 0; mi < 8; ++mi) { MFMA16(a[mi], b0, acc[mi][0]); MFMA16(a[mi], b1, acc[mi][1]); }
    PRIO0;
    GATE2;   // drains (U).B1 before p1 reads it
    BARF();
    // ---- p1: ks=0, B-half1 (up) ----
    b0 = *(const bf16x8*)&B1c[bbase];
    b1 = *(const bf16x8*)&B1c[512 + bbase];
    STG(&Ab[nxt][1][0], pA[1], k1);
    BARF(); LGKM0;
    PRIO1;
#pragma unroll
    for (int mi = 0; mi < 8; ++mi) { MFMA16(a[mi], b0, acc[mi][2]); MFMA16(a[mi], b1, acc[mi][3]); }
    PRIO0;
    BARF();
    // ---- p2: ks=1, B-half0 ----
#pragma unroll
    for (int mi = 0; mi < 8; ++mi) a[mi] = *(const bf16x8*)&Ac[4096 + mi * 512 + abase];
    b0 = *(const bf16x8*)&B0c[4096 + bbase];
    b1 = *(const bf16x8*)&B0c[4096 + 512 + bbase];
    STG(&Bb[nxt][0][0], pB[0], k1);
    BARF(); LGKM0;
    PRIO1;
#pragma unroll
    for (int mi = 0; mi < 8; ++mi) { MFMA16(a[mi], b0, acc[mi][0]); MFMA16(a[mi], b1, acc[mi][1]); }
    PRIO0;
    BARF();
    // ---- p3: ks=1, B-half1 ----
    b0 = *(const bf16x8*)&B1c[4096 + bbase];
    b1 = *(const bf16x8*)&B1c[4096 + 512 + bbase];
    STG(&Bb[nxt][1][0], pB[1], k1);
    BARF(); LGKM0;
    PRIO1;
#pragma unroll
    for (int mi = 0; mi < 8; ++mi) { MFMA16(a[mi], b0, acc[mi][2]); MFMA16(a[mi], b1, acc[mi][3]); }
    PRIO0;
    GATE2;   // drains (U+1).A0/A1/B0 before U+1.p0 reads them
    BARF();
  }
  VM0;  // drain tail stages

  // epilogue: SwiGLU -> h. C/D: col=lane&15, row=(lane>>4)*4+reg
  int quad = lane >> 4;
#pragma unroll
  for (int mi = 0; mi < 8; ++mi)
#pragma unroll
    for (int r = 0; r < 4; ++r) {
      int m = m0 + wm * 128 + mi * 16 + quad * 4 + r;
      if (m < n_e) {
        unsigned short* hp = &h[(long)(base + m) * FDIM];
#pragma unroll
        for (int n = 0; n < 2; ++n) {
          int col = c0 + wn * 32 + n * 16 + fr;
          if (col < FDIM) {
            float g = acc[mi][n][r], u = acc[mi][n + 2][r];
            hp[col] = f2bf((g / (1.f + __expf(-g))) * u);
          }
        }
      }
    }
}

// ---------------- GEMM2: y[slot] = w * (h @ W2), same structure ----------------
// Tile 256 slots x 256 cols, K = 2752 = 43x64 exact. grid (4, 32, 8).
__global__ __launch_bounds__(512, 2) void gemm2_k(
    const unsigned short* __restrict__ hb, const unsigned short* __restrict__ w2t,
    const int* __restrict__ meta, const float* __restrict__ slot_w,
    float* __restrict__ y) {
  int e = blockIdx.z;
  int n_e = meta[e];
  int m0 = blockIdx.y * 256;
  if (m0 >= n_e) return;
  int base = meta[16 + e];
  int c0 = blockIdx.x * 256;
  const unsigned short* wB = w2t + (long)e * DDIM * FDIM;

  __shared__ unsigned short Ab[2][2][8192];
  __shared__ unsigned short Bb[2][2][8192];

  int t = threadIdx.x;
  int lane = t & 63, w = t >> 6;
  int wm = w >> 2, wn = w & 3;
  int fr = lane & 15;

  int rj = lane >> 2;
  int kc = ((lane & 3) ^ ((lane >> 5) & 1) * 2) * 8;
  int sdst = w * 512 + lane * 8;

  const unsigned short* pA[2];
  const unsigned short* pB[2];
#pragma unroll
  for (int hh = 0; hh < 2; ++hh) {
    int tr = hh * 128 + w * 16 + rj;
    int srow = base + min(m0 + tr, n_e - 1);
    pA[hh] = hb + (long)srow * FDIM + kc;
    pB[hh] = wB + (long)(c0 + tr) * FDIM + kc;
  }

  int qp = ((lane >> 4) ^ ((fr >> 3) & 1) * 2) * 8;
  int abase = fr * 32 + qp;
  int bbase = wn * 1024 + fr * 32 + qp;

  f32x4 acc[8][4];
#pragma unroll
  for (int mi = 0; mi < 8; ++mi)
#pragma unroll
    for (int n = 0; n < 4; ++n) acc[mi][n] = (f32x4){0.f, 0.f, 0.f, 0.f};
  bf16x8 a[8], b0, b1;

  STG(&Ab[0][0][0], pA[0], 0);
  STG(&Ab[0][1][0], pA[1], 0);
  STG(&Bb[0][0][0], pB[0], 0);
  STG(&Bb[0][1][0], pB[1], 0);
  VM0;
  BARF();

#pragma unroll 1
  for (int U = 0; U < NT2; ++U) {
    int cur = U & 1, nxt = cur ^ 1;
    const unsigned short* Ac = &Ab[cur][wm][0];
    const unsigned short* B0c = &Bb[cur][0][0];
    const unsigned short* B1c = &Bb[cur][1][0];
    int k1 = ((U + 1) < NT2) ? (U + 1) * 64 : 0;
    // p0
#pragma unroll
    for (int mi = 0; mi < 8; ++mi) a[mi] = *(const bf16x8*)&Ac[mi * 512 + abase];
    b0 = *(const bf16x8*)&B0c[bbase];
    b1 = *(const bf16x8*)&B0c[512 + bbase];
    STG(&Ab[nxt][0][0], pA[0], k1);
    BARF(); LGKM0;
    PRIO1;
#pragma unroll
    for (int mi = 0; mi < 8; ++mi) { MFMA16(a[mi], b0, acc[mi][0]); MFMA16(a[mi], b1, acc[mi][1]); }
    PRIO0;
    GATE2;
    BARF();
    // p1
    b0 = *(const bf16x8*)&B1c[bbase];
    b1 = *(const bf16x8*)&B1c[512 + bbase];
    STG(&Ab[nxt][1][0], pA[1], k1);
    BARF(); LGKM0;
    PRIO1;
#pragma unroll
    for (int mi = 0; mi < 8; ++mi) { MFMA16(a[mi], b0, acc[mi][2]); MFMA16(a[mi], b1, acc[mi][3]); }
    PRIO0;
    BARF();
    // p2
#pragma unroll
    for (int mi = 0; mi < 8; ++mi) a[mi] = *(const bf16x8*)&Ac[4096 + mi * 512 + abase];
    b0 = *(const bf16x8*)&B0c[4096 + bbase];
    b1 = *(const bf16x8*)&B0c[4096 + 512 + bbase];
    STG(&Bb[nxt][0][0], pB[0], k1);
    BARF(); LGKM0;
    PRIO1;
#pragma unroll
    for (int mi = 0; mi < 8; ++mi) { MFMA16(a[mi], b0, acc[mi][0]); MFMA16(a[mi], b1, acc[mi][1]); }
    PRIO0;
    BARF();
    // p3
    b0 = *(const bf16x8*)&B1c[4096 + bbase];
    b1 = *(const bf16x8*)&B1c[4096 + 512 + bbase];
    STG(&Bb[nxt][1][0], pB[1], k1);
    BARF(); LGKM0;
    PRIO1;
#pragma unroll
    for (int mi = 0; mi < 8; ++mi) { MFMA16(a[mi], b0, acc[mi][2]); MFMA16(a[mi], b1, acc[mi][3]); }
    PRIO0;
    GATE2;
    BARF();
  }
  VM0;

  int quad = lane >> 4;
#pragma unroll
  for (int mi = 0; mi < 8; ++mi)
#pragma unroll
    for (int r = 0; r < 4; ++r) {
      int m = m0 + wm * 128 + mi * 16 + quad * 4 + r;
      if (m < n_e) {
        float wgt = slot_w[base + m];
        float* yp = y + (long)(base + m) * DDIM;
#pragma unroll
        for (int n = 0; n < 4; ++n) {
          int col = c0 + (n >> 1) * 128 + wn * 32 + (n & 1) * 16 + fr;
          yp[col] = wgt * acc[mi][n][r];
        }
      }
    }
}

// ---------------- combine: out[tok] = y[slot0] + y[slot1] ----------------
__global__ void combine_k(const float* __restrict__ y, const int2* __restrict__ tok_slot,
                          float* __restrict__ out) {
  int tok = blockIdx.x * 4 + (threadIdx.x >> 6);
  int lane = threadIdx.x & 63;
  int2 s = tok_slot[tok];
  const float4* y0 = (const float4*)(y + (long)s.x * DDIM);
  const float4* y1 = (const float4*)(y + (long)s.y * DDIM);
  float4* o = (float4*)(out + (long)tok * DDIM);
#pragma unroll
  for (int i = 0; i < 4; ++i) {
    float4 u = y0[i * 64 + lane], v = y1[i * 64 + lane];
    o[i * 64 + lane] = make_float4(u.x + v.x, u.y + v.y, u.z + v.z, u.w + v.w);
  }
}

extern "C" void kernel_launch(void* const* d_in, const int* in_sizes, int n_in,
                              void* d_out, int out_size, void* d_ws, size_t ws_size,
                              hipStream_t stream) {
  const float* x   = (const float*)d_in[0];
  const float* W13 = (const float*)d_in[1];
  const float* W2  = (const float*)d_in[2];
  const float* Wr  = (const float*)d_in[3];
  float* out = (float*)d_out;
  char* ws = (char*)d_ws;

  unsigned short* xb   = (unsigned short*)(ws + XB_OFF);
  unsigned short* w13t = (unsigned short*)(ws + W13T_OFF);
  unsigned short* w2t  = (unsigned short*)(ws + W2T_OFF);
  unsigned short* hbuf = (unsigned short*)(ws + H_OFF);
  int*    slot_tok = (int*)(ws + ST_OFF);
  float*  slot_w   = (float*)(ws + SW_OFF);
  int2*   tt_i     = (int2*)(ws + TTI_OFF);
  float2* tt_w     = (float2*)(ws + TTW_OFF);
  int*    meta     = (int*)(ws + META_OFF);
  int2*   tok_slot = (int2*)(ws + TS_OFF);
  float*  ybuf     = (float*)(ws + W13T_OFF);  // aliases W13^T (dead after gemm1)

  hipMemsetAsync(meta, 0, 128, stream);

  cvt_x_k<<<NTOK * DDIM / 4 / 256, 256, 0, stream>>>(x, xb);
  tcvt_k<<<dim3(DF2 / 64, DDIM / 64, NEXP), 256, 0, stream>>>(W13, w13t, DDIM, DF2);
  tcvt_k<<<dim3(DDIM / 64, FDIM / 64, NEXP), 256, 0, stream>>>(W2, w2t, FDIM, DDIM);
  router_k<<<NTOK / 4, 256, 0, stream>>>(x, Wr, meta, tt_i, tt_w);
  offsets_k<<<1, 1, 0, stream>>>(meta);
  scatter_k<<<NTOK / 256, 256, 0, stream>>>(tt_i, tt_w, meta, slot_tok, slot_w, tok_slot);
  gemm1_k<<<dim3(FDIM / 128 + 1, NTOK / 256, NEXP), 512, 0, stream>>>(xb, w13t, meta, slot_tok, hbuf);
  gemm2_k<<<dim3(DDIM / 256, NTOK / 256, NEXP), 512, 0, stream>>>(hbuf, w2t, meta, slot_w, ybuf);
  combine_k<<<NTOK / 4, 256, 0, stream>>>(ybuf, tok_slot, out);
}